// Round 2
// baseline (1926.495 us; speedup 1.0000x reference)
//
#include <hip/hip_runtime.h>
#include <hip/hip_bf16.h>

#define TT 2048
#define BB 8
#define HH 8
#define NNS 32
#define MM (BB * TT)

typedef __attribute__((ext_vector_type(8))) short short8;
typedef __attribute__((ext_vector_type(4))) float f32x4;

__device__ __forceinline__ float bf2f(ushort u) {
    return __uint_as_float(((unsigned)u) << 16);
}
__device__ __forceinline__ ushort f2bf(float f) {
    // round-to-nearest-even bf16 truncation
    unsigned x = __float_as_uint(f);
    unsigned r = (x + 0x7fffu + ((x >> 16) & 1u)) >> 16;
    return (ushort)r;
}
__device__ __forceinline__ float sigmoidf_fast(float x) {
    return 1.0f / (1.0f + __expf(-x));
}
__device__ __forceinline__ float tanhf_fast(float x) {
    x = fminf(15.0f, fmaxf(-15.0f, x));
    float e = __expf(2.0f * x);
    return (e - 1.0f) / (e + 1.0f);
}

// Split 8 fp32 -> bf16 hi + bf16 lo planes, stored as 16B each.
__device__ __forceinline__ void stage8_split(const float* __restrict__ src,
                                             ushort* __restrict__ hi,
                                             ushort* __restrict__ lo) {
    float4 x0 = *reinterpret_cast<const float4*>(src);
    float4 x1 = *reinterpret_cast<const float4*>(src + 4);
    float xs[8] = {x0.x, x0.y, x0.z, x0.w, x1.x, x1.y, x1.z, x1.w};
    ushort h[8], l[8];
#pragma unroll
    for (int i = 0; i < 8; ++i) {
        ushort hh = f2bf(xs[i]);
        h[i] = hh;
        l[i] = f2bf(xs[i] - bf2f(hh));
    }
    *reinterpret_cast<uint4*>(hi) = *reinterpret_cast<const uint4*>(h);
    *reinterpret_cast<uint4*>(lo) = *reinterpret_cast<const uint4*>(l);
}
__device__ __forceinline__ void stage8_hi(const float* __restrict__ src,
                                          ushort* __restrict__ hi) {
    float4 x0 = *reinterpret_cast<const float4*>(src);
    float4 x1 = *reinterpret_cast<const float4*>(src + 4);
    float xs[8] = {x0.x, x0.y, x0.z, x0.w, x1.x, x1.y, x1.z, x1.w};
    ushort h[8];
#pragma unroll
    for (int i = 0; i < 8; ++i) h[i] = f2bf(xs[i]);
    *reinterpret_cast<uint4*>(hi) = *reinterpret_cast<const uint4*>(h);
}

// C[M,N] = act(A[M,K] @ W[N,K]^T), fp32 in/out, split-bf16 MFMA (hi+lo, 3 MFMAs).
// Tile 64x64, BK=32, 256 threads / 4 waves. Padded LDS stride 40 (2-way alias = free).
// ACT: 1 = silu (-> xp), 2 = cols>=768 get sigmoid(x + b_beta[col-768]) (-> P)
template<int ACT>
__global__ __launch_bounds__(256) void gemm_split(
    const float* __restrict__ A,
    const float* __restrict__ W0, const float* __restrict__ W1,
    const float* __restrict__ W2, const float* __restrict__ W3,
    const float* __restrict__ bbeta,
    float* __restrict__ C, int M, int N, int K)
{
    __shared__ __align__(16) ushort Ah[64][40], Al[64][40];
    __shared__ __align__(16) ushort Wh[64][40], Wl[64][40];
    const int n0 = blockIdx.x * 64;
    const int m0 = blockIdx.y * 64;
    const int t  = threadIdx.x;
    const int wave = t >> 6, lane = t & 63;
    const int lr = lane & 15, lq = lane >> 4;

    const float* Wsel;
    {
        int wi = n0 >> 8;
        Wsel = (wi == 0) ? W0 : (wi == 1) ? W1 : (wi == 2) ? W2 : W3;
    }
    const int wr0 = n0 & 255;

    const int ar = t >> 2;        // 0..63 staging row
    const int ak = (t & 3) * 8;   // 0,8,16,24 staging k

    f32x4 acc[4];
#pragma unroll
    for (int c = 0; c < 4; ++c) acc[c] = (f32x4){0.f, 0.f, 0.f, 0.f};

    for (int k0 = 0; k0 < K; k0 += 32) {
        __syncthreads();
        stage8_split(&A[(size_t)(m0 + ar) * K + k0 + ak], &Ah[ar][ak], &Al[ar][ak]);
        stage8_split(&Wsel[(size_t)(wr0 + ar) * K + k0 + ak], &Wh[ar][ak], &Wl[ar][ak]);
        __syncthreads();
        // A frag: lane holds A[m=lane&15][k=(lane>>4)*8+j]
        short8 ah = *reinterpret_cast<const short8*>(&Ah[wave * 16 + lr][lq * 8]);
        short8 al = *reinterpret_cast<const short8*>(&Al[wave * 16 + lr][lq * 8]);
#pragma unroll
        for (int c = 0; c < 4; ++c) {
            // B frag: lane holds B[k=(lane>>4)*8+j][n=lane&15] = W[n][k]
            short8 bh = *reinterpret_cast<const short8*>(&Wh[c * 16 + lr][lq * 8]);
            short8 bl = *reinterpret_cast<const short8*>(&Wl[c * 16 + lr][lq * 8]);
            acc[c] = __builtin_amdgcn_mfma_f32_16x16x32_bf16(ah, bh, acc[c], 0, 0, 0);
            acc[c] = __builtin_amdgcn_mfma_f32_16x16x32_bf16(ah, bl, acc[c], 0, 0, 0);
            acc[c] = __builtin_amdgcn_mfma_f32_16x16x32_bf16(al, bh, acc[c], 0, 0, 0);
        }
    }

    // C/D layout (m89-verified): col = lane&15, row = (lane>>4)*4 + reg
#pragma unroll
    for (int c = 0; c < 4; ++c) {
#pragma unroll
        for (int r2 = 0; r2 < 4; ++r2) {
            int mg = m0 + wave * 16 + lq * 4 + r2;
            int ng = n0 + c * 16 + lr;
            float v = acc[c][r2];
            if (ACT == 1) v = v * sigmoidf_fast(v);
            if (ACT == 2 && ng >= 768) v = sigmoidf_fast(v + bbeta[ng - 768]);
            C[(size_t)mg * N + ng] = v;
        }
    }
}

// GEMM3: A is bf16 (cell), W fp32 -> bf16 hi only, C fp32. Single MFMA.
__global__ __launch_bounds__(256) void gemm_bf_a(
    const ushort* __restrict__ A,
    const float* __restrict__ W0, const float* __restrict__ W1,
    const float* __restrict__ W2, const float* __restrict__ W3,
    float* __restrict__ C, int M, int N, int K)
{
    __shared__ __align__(16) ushort As[64][40];
    __shared__ __align__(16) ushort Ws[64][40];
    const int n0 = blockIdx.x * 64;
    const int m0 = blockIdx.y * 64;
    const int t  = threadIdx.x;
    const int wave = t >> 6, lane = t & 63;
    const int lr = lane & 15, lq = lane >> 4;

    const float* Wsel;
    {
        int wi = n0 >> 8;
        Wsel = (wi == 0) ? W0 : (wi == 1) ? W1 : (wi == 2) ? W2 : W3;
    }
    const int wr0 = n0 & 255;
    const int ar = t >> 2;
    const int ak = (t & 3) * 8;

    f32x4 acc[4];
#pragma unroll
    for (int c = 0; c < 4; ++c) acc[c] = (f32x4){0.f, 0.f, 0.f, 0.f};

    for (int k0 = 0; k0 < K; k0 += 32) {
        __syncthreads();
        *reinterpret_cast<uint4*>(&As[ar][ak]) =
            *reinterpret_cast<const uint4*>(&A[(size_t)(m0 + ar) * K + k0 + ak]);
        stage8_hi(&Wsel[(size_t)(wr0 + ar) * K + k0 + ak], &Ws[ar][ak]);
        __syncthreads();
        short8 af = *reinterpret_cast<const short8*>(&As[wave * 16 + lr][lq * 8]);
#pragma unroll
        for (int c = 0; c < 4; ++c) {
            short8 bfv = *reinterpret_cast<const short8*>(&Ws[c * 16 + lr][lq * 8]);
            acc[c] = __builtin_amdgcn_mfma_f32_16x16x32_bf16(af, bfv, acc[c], 0, 0, 0);
        }
    }

#pragma unroll
    for (int c = 0; c < 4; ++c) {
#pragma unroll
        for (int r2 = 0; r2 < 4; ++r2) {
            int mg = m0 + wave * 16 + lq * 4 + r2;
            int ng = n0 + c * 16 + lr;
            C[(size_t)mg * N + ng] = acc[c][r2];
        }
    }
}

// Recurrent scan, fp32. One thread per S[b,h,i,j]; j-reductions via shfl_xor(32).
__global__ __launch_bounds__(256) void scan_kernel(
    const float* __restrict__ P,
    ushort* __restrict__ cell,     // [B*T, 256] bf16
    float* __restrict__ Sout)      // [B,H,32,32] fp32
{
    int g = blockIdx.x * 256 + threadIdx.x;
    int j = g & 31, i = (g >> 5) & 31, h = (g >> 10) & 7, b = g >> 13;
    const float* pb = P + (size_t)b * TT * 1024;
    const int ok = h * 32 + j;
    const int ov = 256 + h * 32 + i;
    const int oq = 512 + h * 32 + j;
    const int ob = 768 + h * 32 + i;

    float S = 0.f;
    float kj = pb[ok], vi = pb[ov], qj = pb[oq], bi = pb[ob];
    float ks = kj * kj;
    ks += __shfl_xor(ks, 1, 32);  ks += __shfl_xor(ks, 2, 32);
    ks += __shfl_xor(ks, 4, 32);  ks += __shfl_xor(ks, 8, 32);
    ks += __shfl_xor(ks, 16, 32);
    float kn = kj / (sqrtf(ks) + 1e-6f);

    const size_t cbase = (size_t)b * TT * 256 + h * 32 + i;

    for (int t = 0; t < TT; ++t) {
        // prefetch t+1 (off critical path)
        int tn = (t + 1 < TT) ? (t + 1) : t;
        const float* nrow = pb + (size_t)tn * 1024;
        float nk = nrow[ok], nv = nrow[ov], nq = nrow[oq], nb = nrow[ob];

        // retrieved[i] = sum_j S[i,j]*kn[j]   (critical chain)
        float p = S * kn;
        p += __shfl_xor(p, 1, 32);  p += __shfl_xor(p, 2, 32);
        p += __shfl_xor(p, 4, 32);  p += __shfl_xor(p, 8, 32);
        p += __shfl_xor(p, 16, 32);
        float delta = vi - p;
        S = tanhf_fast(fmaf(bi, S, delta * kn));

        // Sq[i] = sum_j S[i,j]*q[j]
        float sq = S * qj;
        sq += __shfl_xor(sq, 1, 32);  sq += __shfl_xor(sq, 2, 32);
        sq += __shfl_xor(sq, 4, 32);  sq += __shfl_xor(sq, 8, 32);
        sq += __shfl_xor(sq, 16, 32);
        if (j == 0) {
            float o = sq * sq * sigmoidf_fast(sq);   // Sq * silu(Sq)
            cell[cbase + (size_t)t * 256] = f2bf(o);
        }

        // next-step kn (independent chain)
        float nks = nk * nk;
        nks += __shfl_xor(nks, 1, 32);  nks += __shfl_xor(nks, 2, 32);
        nks += __shfl_xor(nks, 4, 32);  nks += __shfl_xor(nks, 8, 32);
        nks += __shfl_xor(nks, 16, 32);
        kn = nk / (sqrtf(nks) + 1e-6f);
        vi = nv; qj = nq; bi = nb;
    }

    Sout[(((size_t)(b * HH + h)) * NNS + i) * NNS + j] = S;
}

extern "C" void kernel_launch(void* const* d_in, const int* in_sizes, int n_in,
                              void* d_out, int out_size, void* d_ws, size_t ws_size,
                              hipStream_t stream) {
    const float* x     = (const float*)d_in[0];
    const float* W_in  = (const float*)d_in[1];
    const float* W_k   = (const float*)d_in[2];
    const float* W_v   = (const float*)d_in[3];
    const float* W_q   = (const float*)d_in[4];
    const float* W_b   = (const float*)d_in[5];
    const float* b_b   = (const float*)d_in[6];
    const float* W_out = (const float*)d_in[7];
    float* out = (float*)d_out;

    const int M = MM;                                    // 16384
    float*  xp   = (float*)d_ws;                         // M*1024 fp32
    float*  P    = xp + (size_t)M * 1024;                // M*1024 fp32
    ushort* cell = (ushort*)(P + (size_t)M * 1024);      // M*256 bf16

    dim3 blk(256);
    dim3 g1(1024 / 64, M / 64);

    // 1) xp = silu(x @ W_in^T)   (split-bf16, fp32-accurate)
    gemm_split<1><<<g1, blk, 0, stream>>>(x, W_in, W_in + 256 * 1024,
                                          W_in + 512 * 1024, W_in + 768 * 1024,
                                          b_b, xp, M, 1024, 1024);
    // 2) P = xp @ [Wk;Wv;Wq;Wbeta]^T, beta block: sigmoid(. + b_beta)
    gemm_split<2><<<g1, blk, 0, stream>>>(xp, W_k, W_v, W_q, W_b,
                                          b_b, P, M, 1024, 1024);
    // 3) recurrent scan -> cell (bf16) + S_final (fp32, d_out tail)
    scan_kernel<<<dim3(256), blk, 0, stream>>>(P, cell, out + (size_t)M * 1024);
    // 4) y = cell @ W_out^T
    gemm_bf_a<<<g1, blk, 0, stream>>>(cell, W_out, W_out + 256 * 256,
                                      W_out + 512 * 256, W_out + 768 * 256,
                                      out, M, 1024, 256);
}

// Round 3
// 1262.265 us; speedup vs baseline: 1.5262x; 1.5262x over previous
//
#include <hip/hip_runtime.h>
#include <hip/hip_bf16.h>

#define TT 2048
#define BB 8
#define HH 8
#define NNS 32
#define MM (BB * TT)

typedef __attribute__((ext_vector_type(8))) short short8;
typedef __attribute__((ext_vector_type(4))) float f32x4;

__device__ __forceinline__ float bf2f(ushort u) {
    return __uint_as_float(((unsigned)u) << 16);
}
__device__ __forceinline__ ushort f2bf(float f) {
    unsigned x = __float_as_uint(f);
    unsigned r = (x + 0x7fffu + ((x >> 16) & 1u)) >> 16;
    return (ushort)r;
}
__device__ __forceinline__ float sigmoidf_fast(float x) {
    return 1.0f / (1.0f + __expf(-x));
}
__device__ __forceinline__ float tanhf_fast(float x) {
    x = fminf(15.0f, fmaxf(-15.0f, x));
    float e = __expf(2.0f * x);
    return (e - 1.0f) / (e + 1.0f);
}

// x += x_from_lane(ctrl), DPP on the VALU pipe (no LDS, ~4 cyc dependent)
template<int CTRL>
__device__ __forceinline__ float dpp_add(float x) {
    int y = __builtin_amdgcn_update_dpp(0, __float_as_int(x), CTRL, 0xF, 0xF, true);
    return x + __int_as_float(y);
}
// Full 16-lane rotate-reduce: every lane of each 16-lane row ends with the row sum.
// quad_perm xor1 (0xB1), quad_perm xor2 (0x4E), row_ror:4 (0x124), row_ror:8 (0x128)
__device__ __forceinline__ float red16(float x) {
    x = dpp_add<0xB1>(x);
    x = dpp_add<0x4E>(x);
    x = dpp_add<0x124>(x);
    x = dpp_add<0x128>(x);
    return x;
}

// Split 8 fp32 -> bf16 hi + bf16 lo planes, stored as 16B each.
__device__ __forceinline__ void stage8_split(const float* __restrict__ src,
                                             ushort* __restrict__ hi,
                                             ushort* __restrict__ lo) {
    float4 x0 = *reinterpret_cast<const float4*>(src);
    float4 x1 = *reinterpret_cast<const float4*>(src + 4);
    float xs[8] = {x0.x, x0.y, x0.z, x0.w, x1.x, x1.y, x1.z, x1.w};
    ushort h[8], l[8];
#pragma unroll
    for (int i = 0; i < 8; ++i) {
        ushort hh = f2bf(xs[i]);
        h[i] = hh;
        l[i] = f2bf(xs[i] - bf2f(hh));
    }
    *reinterpret_cast<uint4*>(hi) = *reinterpret_cast<const uint4*>(h);
    *reinterpret_cast<uint4*>(lo) = *reinterpret_cast<const uint4*>(l);
}
__device__ __forceinline__ void stage8_hi(const float* __restrict__ src,
                                          ushort* __restrict__ hi) {
    float4 x0 = *reinterpret_cast<const float4*>(src);
    float4 x1 = *reinterpret_cast<const float4*>(src + 4);
    float xs[8] = {x0.x, x0.y, x0.z, x0.w, x1.x, x1.y, x1.z, x1.w};
    ushort h[8];
#pragma unroll
    for (int i = 0; i < 8; ++i) h[i] = f2bf(xs[i]);
    *reinterpret_cast<uint4*>(hi) = *reinterpret_cast<const uint4*>(h);
}

// C[M,N] = act(A[M,K] @ W[N,K]^T), fp32 in/out, split-bf16 MFMA (hi+lo, 3 MFMAs).
template<int ACT>
__global__ __launch_bounds__(256) void gemm_split(
    const float* __restrict__ A,
    const float* __restrict__ W0, const float* __restrict__ W1,
    const float* __restrict__ W2, const float* __restrict__ W3,
    const float* __restrict__ bbeta,
    float* __restrict__ C, int M, int N, int K)
{
    __shared__ __align__(16) ushort Ah[64][40], Al[64][40];
    __shared__ __align__(16) ushort Wh[64][40], Wl[64][40];
    const int n0 = blockIdx.x * 64;
    const int m0 = blockIdx.y * 64;
    const int t  = threadIdx.x;
    const int wave = t >> 6, lane = t & 63;
    const int lr = lane & 15, lq = lane >> 4;

    const float* Wsel;
    {
        int wi = n0 >> 8;
        Wsel = (wi == 0) ? W0 : (wi == 1) ? W1 : (wi == 2) ? W2 : W3;
    }
    const int wr0 = n0 & 255;
    const int ar = t >> 2;
    const int ak = (t & 3) * 8;

    f32x4 acc[4];
#pragma unroll
    for (int c = 0; c < 4; ++c) acc[c] = (f32x4){0.f, 0.f, 0.f, 0.f};

    for (int k0 = 0; k0 < K; k0 += 32) {
        __syncthreads();
        stage8_split(&A[(size_t)(m0 + ar) * K + k0 + ak], &Ah[ar][ak], &Al[ar][ak]);
        stage8_split(&Wsel[(size_t)(wr0 + ar) * K + k0 + ak], &Wh[ar][ak], &Wl[ar][ak]);
        __syncthreads();
        short8 ah = *reinterpret_cast<const short8*>(&Ah[wave * 16 + lr][lq * 8]);
        short8 al = *reinterpret_cast<const short8*>(&Al[wave * 16 + lr][lq * 8]);
#pragma unroll
        for (int c = 0; c < 4; ++c) {
            short8 bh = *reinterpret_cast<const short8*>(&Wh[c * 16 + lr][lq * 8]);
            short8 bl = *reinterpret_cast<const short8*>(&Wl[c * 16 + lr][lq * 8]);
            acc[c] = __builtin_amdgcn_mfma_f32_16x16x32_bf16(ah, bh, acc[c], 0, 0, 0);
            acc[c] = __builtin_amdgcn_mfma_f32_16x16x32_bf16(ah, bl, acc[c], 0, 0, 0);
            acc[c] = __builtin_amdgcn_mfma_f32_16x16x32_bf16(al, bh, acc[c], 0, 0, 0);
        }
    }

#pragma unroll
    for (int c = 0; c < 4; ++c) {
#pragma unroll
        for (int r2 = 0; r2 < 4; ++r2) {
            int mg = m0 + wave * 16 + lq * 4 + r2;
            int ng = n0 + c * 16 + lr;
            float v = acc[c][r2];
            if (ACT == 1) v = v * sigmoidf_fast(v);
            if (ACT == 2 && ng >= 768) v = sigmoidf_fast(v + bbeta[ng - 768]);
            C[(size_t)mg * N + ng] = v;
        }
    }
}

// GEMM3: A is bf16 (cell), W fp32 -> bf16 hi only, C fp32.
__global__ __launch_bounds__(256) void gemm_bf_a(
    const ushort* __restrict__ A,
    const float* __restrict__ W0, const float* __restrict__ W1,
    const float* __restrict__ W2, const float* __restrict__ W3,
    float* __restrict__ C, int M, int N, int K)
{
    __shared__ __align__(16) ushort As[64][40];
    __shared__ __align__(16) ushort Ws[64][40];
    const int n0 = blockIdx.x * 64;
    const int m0 = blockIdx.y * 64;
    const int t  = threadIdx.x;
    const int wave = t >> 6, lane = t & 63;
    const int lr = lane & 15, lq = lane >> 4;

    const float* Wsel;
    {
        int wi = n0 >> 8;
        Wsel = (wi == 0) ? W0 : (wi == 1) ? W1 : (wi == 2) ? W2 : W3;
    }
    const int wr0 = n0 & 255;
    const int ar = t >> 2;
    const int ak = (t & 3) * 8;

    f32x4 acc[4];
#pragma unroll
    for (int c = 0; c < 4; ++c) acc[c] = (f32x4){0.f, 0.f, 0.f, 0.f};

    for (int k0 = 0; k0 < K; k0 += 32) {
        __syncthreads();
        *reinterpret_cast<uint4*>(&As[ar][ak]) =
            *reinterpret_cast<const uint4*>(&A[(size_t)(m0 + ar) * K + k0 + ak]);
        stage8_hi(&Wsel[(size_t)(wr0 + ar) * K + k0 + ak], &Ws[ar][ak]);
        __syncthreads();
        short8 af = *reinterpret_cast<const short8*>(&As[wave * 16 + lr][lq * 8]);
#pragma unroll
        for (int c = 0; c < 4; ++c) {
            short8 bfv = *reinterpret_cast<const short8*>(&Ws[c * 16 + lr][lq * 8]);
            acc[c] = __builtin_amdgcn_mfma_f32_16x16x32_bf16(af, bfv, acc[c], 0, 0, 0);
        }
    }

#pragma unroll
    for (int c = 0; c < 4; ++c) {
#pragma unroll
        for (int r2 = 0; r2 < 4; ++r2) {
            int mg = m0 + wave * 16 + lq * 4 + r2;
            int ng = n0 + c * 16 + lr;
            C[(size_t)mg * N + ng] = acc[c][r2];
        }
    }
}

// Recurrent scan, fp32, DPP-only reductions (no LDS, no barriers).
// Thread g -> (b, h, row i, lane l in 16-group); holds S[i][l] and S[i][l+16].
// All j-reductions are 16-lane DPP rotate-reduces (every lane gets the sum).
__global__ __launch_bounds__(64) void scan_kernel(
    const float* __restrict__ P,
    ushort* __restrict__ cell,     // [B*T, 256] bf16
    float* __restrict__ Sout)      // [B,H,32,32] fp32
{
    int g = blockIdx.x * 64 + threadIdx.x;   // 32768 threads
    int l = g & 15;
    int i = (g >> 4) & 31;
    int h = (g >> 9) & 7;
    int b = g >> 12;
    const float* pb = P + (size_t)b * TT * 1024;
    const int ok0 = h * 32 + l,        ok1 = ok0 + 16;
    const int oq0 = 512 + h * 32 + l,  oq1 = oq0 + 16;
    const int ov  = 256 + h * 32 + i;
    const int ob  = 768 + h * 32 + i;

    float S0 = 0.f, S1 = 0.f;
    // t=0 inputs + kn
    float k0 = pb[ok0], k1 = pb[ok1];
    float q0 = pb[oq0], q1 = pb[oq1];
    float vi = pb[ov],  bi = pb[ob];
    float ks = red16(fmaf(k1, k1, k0 * k0));
    float inv = 1.0f / (sqrtf(ks) + 1e-6f);
    float kn0 = k0 * inv, kn1 = k1 * inv;

    const size_t cbase = (size_t)b * TT * 256 + h * 32 + i;

    for (int t = 0; t < TT; ++t) {
        // prefetch t+1 (off critical path)
        int tn = (t + 1 < TT) ? (t + 1) : t;
        const float* nrow = pb + (size_t)tn * 1024;
        float nk0 = nrow[ok0], nk1 = nrow[ok1];
        float nq0 = nrow[oq0], nq1 = nrow[oq1];
        float nv  = nrow[ov],  nb  = nrow[ob];

        // retrieved[i] = sum_j S[i,j]*kn[j]  (critical chain: 2 fma + 4 DPP)
        float p = red16(fmaf(S1, kn1, S0 * kn0));
        float delta = vi - p;
        S0 = tanhf_fast(fmaf(bi, S0, delta * kn0));
        S1 = tanhf_fast(fmaf(bi, S1, delta * kn1));

        // Sq[i] = sum_j S[i,j]*q[j]
        float sq = red16(fmaf(S1, q1, S0 * q0));
        if (l == 0) {
            float o = sq * sq * sigmoidf_fast(sq);   // Sq * silu(Sq)
            cell[cbase + (size_t)t * 256] = f2bf(o);
        }

        // next-step kn (independent chain)
        float nks = red16(fmaf(nk1, nk1, nk0 * nk0));
        inv = 1.0f / (sqrtf(nks) + 1e-6f);
        kn0 = nk0 * inv; kn1 = nk1 * inv;
        vi = nv; bi = nb; q0 = nq0; q1 = nq1;
    }

    float* so = Sout + (((size_t)(b * HH + h)) * NNS + i) * NNS;
    so[l] = S0;
    so[l + 16] = S1;
}

extern "C" void kernel_launch(void* const* d_in, const int* in_sizes, int n_in,
                              void* d_out, int out_size, void* d_ws, size_t ws_size,
                              hipStream_t stream) {
    const float* x     = (const float*)d_in[0];
    const float* W_in  = (const float*)d_in[1];
    const float* W_k   = (const float*)d_in[2];
    const float* W_v   = (const float*)d_in[3];
    const float* W_q   = (const float*)d_in[4];
    const float* W_b   = (const float*)d_in[5];
    const float* b_b   = (const float*)d_in[6];
    const float* W_out = (const float*)d_in[7];
    float* out = (float*)d_out;

    const int M = MM;                                    // 16384
    float*  xp   = (float*)d_ws;                         // M*1024 fp32
    float*  P    = xp + (size_t)M * 1024;                // M*1024 fp32
    ushort* cell = (ushort*)(P + (size_t)M * 1024);      // M*256 bf16

    dim3 blk(256);
    dim3 g1(1024 / 64, M / 64);

    // 1) xp = silu(x @ W_in^T)
    gemm_split<1><<<g1, blk, 0, stream>>>(x, W_in, W_in + 256 * 1024,
                                          W_in + 512 * 1024, W_in + 768 * 1024,
                                          b_b, xp, M, 1024, 1024);
    // 2) P = xp @ [Wk;Wv;Wq;Wbeta]^T, beta block: sigmoid(. + b_beta)
    gemm_split<2><<<g1, blk, 0, stream>>>(xp, W_k, W_v, W_q, W_b,
                                          b_b, P, M, 1024, 1024);
    // 3) recurrent scan -> cell (bf16) + S_final (fp32, d_out tail)
    scan_kernel<<<dim3(32768 / 64), dim3(64), 0, stream>>>(P, cell, out + (size_t)M * 1024);
    // 4) y = cell @ W_out^T
    gemm_bf_a<<<g1, blk, 0, stream>>>(cell, W_out, W_out + 256 * 256,
                                      W_out + 512 * 256, W_out + 768 * 256,
                                      out, M, 1024, 256);
}

// Round 4
// 879.106 us; speedup vs baseline: 2.1914x; 1.4359x over previous
//
#include <hip/hip_runtime.h>
#include <hip/hip_bf16.h>

#define TT 2048
#define BB 8
#define HH 8
#define NNS 32
#define MM (BB * TT)

typedef __attribute__((ext_vector_type(8))) short short8;
typedef __attribute__((ext_vector_type(4))) float f32x4;

__device__ __forceinline__ float bf2f(ushort u) {
    return __uint_as_float(((unsigned)u) << 16);
}
__device__ __forceinline__ ushort f2bf(float f) {
    unsigned x = __float_as_uint(f);
    unsigned r = (x + 0x7fffu + ((x >> 16) & 1u)) >> 16;
    return (ushort)r;
}
__device__ __forceinline__ float sigmoidf_fast(float x) {
    return __builtin_amdgcn_rcpf(1.0f + __expf(-x));
}
__device__ __forceinline__ float tanhf_fast(float x) {
    x = fminf(15.0f, fmaxf(-15.0f, x));
    float e = __expf(2.0f * x);
    return 1.0f - 2.0f * __builtin_amdgcn_rcpf(e + 1.0f);   // (e-1)/(e+1)
}

// x += x_from_lane(ctrl), DPP on the VALU pipe (no LDS, ~4 cyc dependent)
template<int CTRL>
__device__ __forceinline__ float dpp_add(float x) {
    int y = __builtin_amdgcn_update_dpp(0, __float_as_int(x), CTRL, 0xF, 0xF, true);
    return x + __int_as_float(y);
}
// 16-lane rotate-reduce: every lane of each 16-lane row ends with the row sum.
__device__ __forceinline__ float red16(float x) {
    x = dpp_add<0xB1>(x);    // quad_perm xor1
    x = dpp_add<0x4E>(x);    // quad_perm xor2
    x = dpp_add<0x124>(x);   // row_ror:4
    x = dpp_add<0x128>(x);   // row_ror:8
    return x;
}

// Split 8 fp32 -> bf16 hi + bf16 lo planes, stored as 16B each.
__device__ __forceinline__ void stage8_split(const float* __restrict__ src,
                                             ushort* __restrict__ hi,
                                             ushort* __restrict__ lo) {
    float4 x0 = *reinterpret_cast<const float4*>(src);
    float4 x1 = *reinterpret_cast<const float4*>(src + 4);
    float xs[8] = {x0.x, x0.y, x0.z, x0.w, x1.x, x1.y, x1.z, x1.w};
    ushort h[8], l[8];
#pragma unroll
    for (int i = 0; i < 8; ++i) {
        ushort hh = f2bf(xs[i]);
        h[i] = hh;
        l[i] = f2bf(xs[i] - bf2f(hh));
    }
    *reinterpret_cast<uint4*>(hi) = *reinterpret_cast<const uint4*>(h);
    *reinterpret_cast<uint4*>(lo) = *reinterpret_cast<const uint4*>(l);
}
__device__ __forceinline__ void stage8_hi(const float* __restrict__ src,
                                          ushort* __restrict__ hi) {
    float4 x0 = *reinterpret_cast<const float4*>(src);
    float4 x1 = *reinterpret_cast<const float4*>(src + 4);
    float xs[8] = {x0.x, x0.y, x0.z, x0.w, x1.x, x1.y, x1.z, x1.w};
    ushort h[8];
#pragma unroll
    for (int i = 0; i < 8; ++i) h[i] = f2bf(xs[i]);
    *reinterpret_cast<uint4*>(hi) = *reinterpret_cast<const uint4*>(h);
}

// C[M,N] = act(A[M,K] @ W[N,K]^T), fp32 in/out, split-bf16 MFMA (hi+lo, 3 MFMAs).
template<int ACT>
__global__ __launch_bounds__(256) void gemm_split(
    const float* __restrict__ A,
    const float* __restrict__ W0, const float* __restrict__ W1,
    const float* __restrict__ W2, const float* __restrict__ W3,
    const float* __restrict__ bbeta,
    float* __restrict__ C, int M, int N, int K)
{
    __shared__ __align__(16) ushort Ah[64][40], Al[64][40];
    __shared__ __align__(16) ushort Wh[64][40], Wl[64][40];
    const int n0 = blockIdx.x * 64;
    const int m0 = blockIdx.y * 64;
    const int t  = threadIdx.x;
    const int wave = t >> 6, lane = t & 63;
    const int lr = lane & 15, lq = lane >> 4;

    const float* Wsel;
    {
        int wi = n0 >> 8;
        Wsel = (wi == 0) ? W0 : (wi == 1) ? W1 : (wi == 2) ? W2 : W3;
    }
    const int wr0 = n0 & 255;
    const int ar = t >> 2;
    const int ak = (t & 3) * 8;

    f32x4 acc[4];
#pragma unroll
    for (int c = 0; c < 4; ++c) acc[c] = (f32x4){0.f, 0.f, 0.f, 0.f};

    for (int k0 = 0; k0 < K; k0 += 32) {
        __syncthreads();
        stage8_split(&A[(size_t)(m0 + ar) * K + k0 + ak], &Ah[ar][ak], &Al[ar][ak]);
        stage8_split(&Wsel[(size_t)(wr0 + ar) * K + k0 + ak], &Wh[ar][ak], &Wl[ar][ak]);
        __syncthreads();
        short8 ah = *reinterpret_cast<const short8*>(&Ah[wave * 16 + lr][lq * 8]);
        short8 al = *reinterpret_cast<const short8*>(&Al[wave * 16 + lr][lq * 8]);
#pragma unroll
        for (int c = 0; c < 4; ++c) {
            short8 bh = *reinterpret_cast<const short8*>(&Wh[c * 16 + lr][lq * 8]);
            short8 bl = *reinterpret_cast<const short8*>(&Wl[c * 16 + lr][lq * 8]);
            acc[c] = __builtin_amdgcn_mfma_f32_16x16x32_bf16(ah, bh, acc[c], 0, 0, 0);
            acc[c] = __builtin_amdgcn_mfma_f32_16x16x32_bf16(ah, bl, acc[c], 0, 0, 0);
            acc[c] = __builtin_amdgcn_mfma_f32_16x16x32_bf16(al, bh, acc[c], 0, 0, 0);
        }
    }

#pragma unroll
    for (int c = 0; c < 4; ++c) {
#pragma unroll
        for (int r2 = 0; r2 < 4; ++r2) {
            int mg = m0 + wave * 16 + lq * 4 + r2;
            int ng = n0 + c * 16 + lr;
            float v = acc[c][r2];
            if (ACT == 1) v = v * sigmoidf_fast(v);
            if (ACT == 2 && ng >= 768) v = sigmoidf_fast(v + bbeta[ng - 768]);
            C[(size_t)mg * N + ng] = v;
        }
    }
}

// GEMM3: A is bf16 (cell), W fp32 -> bf16 hi only, C fp32.
__global__ __launch_bounds__(256) void gemm_bf_a(
    const ushort* __restrict__ A,
    const float* __restrict__ W0, const float* __restrict__ W1,
    const float* __restrict__ W2, const float* __restrict__ W3,
    float* __restrict__ C, int M, int N, int K)
{
    __shared__ __align__(16) ushort As[64][40];
    __shared__ __align__(16) ushort Ws[64][40];
    const int n0 = blockIdx.x * 64;
    const int m0 = blockIdx.y * 64;
    const int t  = threadIdx.x;
    const int wave = t >> 6, lane = t & 63;
    const int lr = lane & 15, lq = lane >> 4;

    const float* Wsel;
    {
        int wi = n0 >> 8;
        Wsel = (wi == 0) ? W0 : (wi == 1) ? W1 : (wi == 2) ? W2 : W3;
    }
    const int wr0 = n0 & 255;
    const int ar = t >> 2;
    const int ak = (t & 3) * 8;

    f32x4 acc[4];
#pragma unroll
    for (int c = 0; c < 4; ++c) acc[c] = (f32x4){0.f, 0.f, 0.f, 0.f};

    for (int k0 = 0; k0 < K; k0 += 32) {
        __syncthreads();
        *reinterpret_cast<uint4*>(&As[ar][ak]) =
            *reinterpret_cast<const uint4*>(&A[(size_t)(m0 + ar) * K + k0 + ak]);
        stage8_hi(&Wsel[(size_t)(wr0 + ar) * K + k0 + ak], &Ws[ar][ak]);
        __syncthreads();
        short8 af = *reinterpret_cast<const short8*>(&As[wave * 16 + lr][lq * 8]);
#pragma unroll
        for (int c = 0; c < 4; ++c) {
            short8 bfv = *reinterpret_cast<const short8*>(&Ws[c * 16 + lr][lq * 8]);
            acc[c] = __builtin_amdgcn_mfma_f32_16x16x32_bf16(af, bfv, acc[c], 0, 0, 0);
        }
    }

#pragma unroll
    for (int c = 0; c < 4; ++c) {
#pragma unroll
        for (int r2 = 0; r2 < 4; ++r2) {
            int mg = m0 + wave * 16 + lq * 4 + r2;
            int ng = n0 + c * 16 + lr;
            C[(size_t)mg * N + ng] = acc[c][r2];
        }
    }
}

// Recurrent scan, fp32, DPP reductions, distance-3 register prefetch pipeline,
// XCD-local batch mapping (b = blockIdx & 7 -> heuristic round-robin XCD match).
__global__ __launch_bounds__(64) void scan_kernel(
    const float* __restrict__ P,
    ushort* __restrict__ cell,     // [B*T, 256] bf16
    float* __restrict__ Sout)      // [B,H,32,32] fp32
{
    const int b  = blockIdx.x & 7;           // XCD-local batch slice
    const int r  = blockIdx.x >> 3;          // 0..63
    const int h  = r & 7;
    const int ig = r >> 3;                   // 0..7
    const int l  = threadIdx.x & 15;
    const int i  = ig * 4 + (threadIdx.x >> 4);

    const float* pb = P + (size_t)b * TT * 1024;
    const int ok0 = h * 32 + l,       ok1 = ok0 + 16;
    const int oq0 = 512 + h * 32 + l, oq1 = oq0 + 16;
    const int ov  = 256 + h * 32 + i;
    const int ob  = 768 + h * 32 + i;

    // rotating prefetch file: row t stored in slot t&3
    float rk0[4], rk1[4], rq0[4], rq1[4], rv[4], rb[4];
#pragma unroll
    for (int d = 0; d < 3; ++d) {
        const float* row = pb + (size_t)d * 1024;
        rk0[d] = row[ok0]; rk1[d] = row[ok1];
        rq0[d] = row[oq0]; rq1[d] = row[oq1];
        rv[d]  = row[ov];  rb[d]  = row[ob];
    }
    // cur = step 0
    float ks  = red16(fmaf(rk1[0], rk1[0], rk0[0] * rk0[0]));
    float inv = __builtin_amdgcn_rcpf(__builtin_amdgcn_sqrtf(ks) + 1e-6f);
    float kn0 = rk0[0] * inv, kn1 = rk1[0] * inv;
    float q0 = rq0[0], q1 = rq1[0], vi = rv[0], bi = rb[0];

    float S0 = 0.f, S1 = 0.f;
    const size_t cbase = (size_t)b * TT * 256 + h * 32 + i;

#pragma unroll 4
    for (int t = 0; t < TT; ++t) {
        // stage 1: issue loads for row t+3 (lands ~2 iterations later)
        {
            int rr = (t + 3 < TT) ? (t + 3) : (TT - 1);
            int d3 = (t + 3) & 3;
            const float* row = pb + (size_t)rr * 1024;
            rk0[d3] = row[ok0]; rk1[d3] = row[ok1];
            rq0[d3] = row[oq0]; rq1[d3] = row[oq1];
            rv[d3]  = row[ov];  rb[d3]  = row[ob];
        }

        // stage 2: step t (critical chain)
        float p = red16(fmaf(S1, kn1, S0 * kn0));
        float delta = vi - p;
        S0 = tanhf_fast(fmaf(bi, S0, delta * kn0));
        S1 = tanhf_fast(fmaf(bi, S1, delta * kn1));

        float sq = red16(fmaf(S1, q1, S0 * q0));
        if (l == 0) {
            float o = sq * sq * sigmoidf_fast(sq);   // Sq * silu(Sq)
            cell[cbase + (size_t)t * 256] = f2bf(o);
        }

        // stage 3: prepare cur for step t+1 from row loaded 2 iterations ago
        {
            int d1 = (t + 1) & 3;
            float nks = red16(fmaf(rk1[d1], rk1[d1], rk0[d1] * rk0[d1]));
            inv = __builtin_amdgcn_rcpf(__builtin_amdgcn_sqrtf(nks) + 1e-6f);
            kn0 = rk0[d1] * inv; kn1 = rk1[d1] * inv;
            q0 = rq0[d1]; q1 = rq1[d1]; vi = rv[d1]; bi = rb[d1];
        }
    }

    float* so = Sout + (((size_t)(b * HH + h)) * NNS + i) * NNS;
    so[l] = S0;
    so[l + 16] = S1;
}

extern "C" void kernel_launch(void* const* d_in, const int* in_sizes, int n_in,
                              void* d_out, int out_size, void* d_ws, size_t ws_size,
                              hipStream_t stream) {
    const float* x     = (const float*)d_in[0];
    const float* W_in  = (const float*)d_in[1];
    const float* W_k   = (const float*)d_in[2];
    const float* W_v   = (const float*)d_in[3];
    const float* W_q   = (const float*)d_in[4];
    const float* W_b   = (const float*)d_in[5];
    const float* b_b   = (const float*)d_in[6];
    const float* W_out = (const float*)d_in[7];
    float* out = (float*)d_out;

    const int M = MM;                                    // 16384
    float*  xp   = (float*)d_ws;                         // M*1024 fp32
    float*  P    = xp + (size_t)M * 1024;                // M*1024 fp32
    ushort* cell = (ushort*)(P + (size_t)M * 1024);      // M*256 bf16

    dim3 blk(256);
    dim3 g1(1024 / 64, M / 64);

    // 1) xp = silu(x @ W_in^T)
    gemm_split<1><<<g1, blk, 0, stream>>>(x, W_in, W_in + 256 * 1024,
                                          W_in + 512 * 1024, W_in + 768 * 1024,
                                          b_b, xp, M, 1024, 1024);
    // 2) P = xp @ [Wk;Wv;Wq;Wbeta]^T, beta block: sigmoid(. + b_beta)
    gemm_split<2><<<g1, blk, 0, stream>>>(xp, W_k, W_v, W_q, W_b,
                                          b_b, P, M, 1024, 1024);
    // 3) recurrent scan -> cell (bf16) + S_final (fp32, d_out tail)
    scan_kernel<<<dim3(512), dim3(64), 0, stream>>>(P, cell, out + (size_t)M * 1024);
    // 4) y = cell @ W_out^T
    gemm_bf_a<<<g1, blk, 0, stream>>>(cell, W_out, W_out + 256 * 256,
                                      W_out + 512 * 256, W_out + 768 * 256,
                                      out, M, 1024, 256);
}